// Round 3
// baseline (349.188 us; speedup 1.0000x reference)
//
#include <hip/hip_runtime.h>

// ObjectRelationNetwork on MI355X — barrier-free main-loop revision, RNE-safe.
//
// dur_us 316.8 = harness re-poison fill (~153 us, fixed) + prep + orn_main (~155 us).
// orn_main roofline = 252.6 MB e-write = ~40 us @6.3 TB/s. Old version serialized
// h-build/GEMM/store via 2 barriers/chunk (vmcnt(0) drain) at 2 blocks/CU.
// This version:
//  - h fragments built in registers from ULs/VLs -> ZERO barriers in the K-loop
//  - LDS 64->32 KB, __launch_bounds__(256,4) -> 4 blocks/CU (960 blocks resident)
//  - swapped MFMA operands (A=W2, B=h): lane holds 4 consecutive o -> f32x4 nt stores
//  - W1 pre-converted to bf16 fragment layout in prep kernel
//  - ALL bf16 conversions via explicit RNE bit-twiddle f2bf. Round-2 lesson:
//    inline-asm v_cvt_pk_bf16_f32 produced absmax 0.407 (vs 0.016 with f2bf) —
//    rounding-mode deviation (truncation bias over K=256 of non-negative h).

typedef __attribute__((ext_vector_type(8))) short bf16x8;   // 8 bf16 = 4 VGPRs
typedef __attribute__((ext_vector_type(4))) float f32x4;    // MFMA C/D, nt stores
typedef __attribute__((ext_vector_type(4))) unsigned u32x4;
typedef __attribute__((ext_vector_type(2))) unsigned u32x2;

#define MFMA16(a, b, c) __builtin_amdgcn_mfma_f32_16x16x32_bf16((a), (b), (c), 0, 0, 0)
#define E_ELEMS 62914560ull   // 240*1024*256 e floats, then 245760 all_is_obj floats

__device__ __forceinline__ short f2bf(float f) {          // RNE float->bf16
  unsigned u = __builtin_bit_cast(unsigned, f);
  u += 0x7fffu + ((u >> 16) & 1u);
  return (short)(u >> 16);
}
__device__ __forceinline__ unsigned pack2(short lo, short hi) {
  return (unsigned)(unsigned short)lo | ((unsigned)(unsigned short)hi << 16);
}

// h-fragment: relu(u+v) elementwise on 8 bf16, repacked to bf16 (RNE).
__device__ __forceinline__ bf16x8 hfrag2(bf16x8 u, bf16x8 v) {
  u32x4 uu = __builtin_bit_cast(u32x4, u);
  u32x4 vv = __builtin_bit_cast(u32x4, v);
  u32x4 r;
#pragma unroll
  for (int k = 0; k < 4; k++) {
    float lo = __builtin_bit_cast(float, uu[k] << 16) +
               __builtin_bit_cast(float, vv[k] << 16);
    float hi = __builtin_bit_cast(float, uu[k] & 0xffff0000u) +
               __builtin_bit_cast(float, vv[k] & 0xffff0000u);
    r[k] = pack2(f2bf(fmaxf(lo, 0.f)), f2bf(fmaxf(hi, 0.f)));
  }
  return __builtin_bit_cast(bf16x8, r);
}

// ---- prep: W2 (256x256) -> W2L[kb=k>>3][n][k&7]  (K=256, fragment layout)
//            W1 (256x256) -> W1L[part][kb][n][jj]  (part 0: d 0..127 (U),
//                                                   part 1: d 128..255 (V))
__global__ void prep_weights(const float* __restrict__ W2, const float* __restrict__ W1,
                             short* __restrict__ W2L, short* __restrict__ W1L) {
  int t = blockIdx.x * 256 + threadIdx.x;   // 0..16383
  const float* src;
  short* dst;
  if (t < 8192) {
    int kb = t >> 8, n = t & 255;
    src = W2 + (size_t)n * 256 + kb * 8;
    dst = W2L + (size_t)t * 8;
  } else {
    int u = t - 8192;                       // 0..8191
    int part = u >> 12, kb = (u >> 8) & 15, n = u & 255;
    src = W1 + (size_t)n * 256 + part * 128 + kb * 8;
    dst = W1L + (size_t)u * 8;
  }
  float4 x = *(const float4*)src;
  float4 y = *(const float4*)(src + 4);
  bf16x8 f;
  f[0] = f2bf(x.x); f[1] = f2bf(x.y); f[2] = f2bf(x.z); f[3] = f2bf(x.w);
  f[4] = f2bf(y.x); f[5] = f2bf(y.y); f[6] = f2bf(y.z); f[7] = f2bf(y.w);
  *(bf16x8*)dst = f;
}

// ---- main: 960 blocks (4 per (b,t)), 256 threads. LDS 32 KB -> 4 WG/CU.
__global__ __launch_bounds__(256, 4) void orn_main(
    const float* __restrict__ objs, const float* __restrict__ b1,
    const float* __restrict__ b2, const short* __restrict__ W1L,
    const short* __restrict__ W2L, float* __restrict__ out) {
  __shared__ short ULs[32 * 32 * 8];   // [kb=o>>3][i][o&7]  bf16 of U' = O@W1a^T + b1
  __shared__ short VLs[32 * 32 * 8];   // [kb][j][jj]        bf16 of V  = O@W1b^T

  float* psum  = (float*)ULs;          // phase-1 scratch aliases (dead after sync3)
  float* fclip = (float*)VLs;

  const int tid = threadIdx.x;
  const int bid = blockIdx.x;
  const int bt  = bid >> 2;            // 0..239
  const int q   = bid & 3;             // row-quarter of this (b,t) slab
  const int b   = bt / 15;
  const int tm  = bt - b * 15;         // t-1
  const float* O = objs + (size_t)(b * 16 + tm + 1) * (32 * 128);

  const int lane = tid & 63;
  const int w    = tid >> 6;           // wave 0..3
  const int l15  = lane & 15;
  const int quad = lane >> 4;
  const int n0   = w * 64;             // this wave's o-col base (N split 4x64)

  // ---------------- Phase 1: fp32 row sums -> all_is_obj ----------------
  {
    int i = tid >> 3, c = tid & 7;
    const float* p = O + i * 128 + c * 16;
    float s = 0.f;
#pragma unroll
    for (int e = 0; e < 4; e++) {
      float4 v = *(const float4*)(p + e * 4);
      s += v.x + v.y + v.z + v.w;
    }
    psum[tid] = s;
  }
  __syncthreads();                     // sync1
  if (tid < 32) {
    float s = 0.f;
#pragma unroll
    for (int c = 0; c < 8; c++) s += psum[tid * 8 + c];
    fclip[tid] = fminf(fmaxf(s, 0.f), 1.f);
  }
  __syncthreads();                     // sync2
  {
    int p = q * 256 + tid;             // this WG's 256 pairs
    int i = p >> 5, j = p & 31;
    float v = fclip[i] * fclip[j] * (float)(tm + 1);
    out[E_ELEMS + (size_t)bt * 1024 + p] = fminf(fmaxf(v, 0.f), 1.f);
  }

  // ------- Phase 2: U',V (32 objs x 256 hidden) via MFMA, swapped operands -------
  // A = W1L (M = o rows), B = O (N = i cols).  D: row=quad*4+r -> o, col=l15 -> i.
  {
    // B-fragments from O: B[k = ks*32+quad*8+jj][i = ni*16+l15]
    bf16x8 bfr[2][4];
#pragma unroll
    for (int ni = 0; ni < 2; ni++)
#pragma unroll
      for (int ks = 0; ks < 4; ks++) {
        const float* p = O + (ni * 16 + l15) * 128 + ks * 32 + quad * 8;
        float4 x = *(const float4*)p;
        float4 y = *(const float4*)(p + 4);
        bf16x8 f;
        f[0] = f2bf(x.x); f[1] = f2bf(x.y); f[2] = f2bf(x.z); f[3] = f2bf(x.w);
        f[4] = f2bf(y.x); f[5] = f2bf(y.y); f[6] = f2bf(y.z); f[7] = f2bf(y.w);
        bfr[ni][ks] = f;
      }
    const f32x4 zf = {0.f, 0.f, 0.f, 0.f};
    f32x4 aU[4][2], aV[4][2];
#pragma unroll
    for (int ms = 0; ms < 4; ms++)
#pragma unroll
      for (int ni = 0; ni < 2; ni++) { aU[ms][ni] = zf; aV[ms][ni] = zf; }
#pragma unroll
    for (int ks = 0; ks < 4; ks++) {
      const int kb = ks * 4 + quad;    // 0..15 (K=128 per part)
#pragma unroll
      for (int ms = 0; ms < 4; ms++) {
        const int n = n0 + ms * 16 + l15;
        bf16x8 au = *(const bf16x8*)&W1L[(size_t)((kb << 8) + n) * 8];
        bf16x8 av = *(const bf16x8*)&W1L[(size_t)(4096 + (kb << 8) + n) * 8];
#pragma unroll
        for (int ni = 0; ni < 2; ni++) {
          aU[ms][ni] = MFMA16(au, bfr[ni][ks], aU[ms][ni]);
          aV[ms][ni] = MFMA16(av, bfr[ni][ks], aV[ms][ni]);
        }
      }
    }
    __syncthreads();                   // sync3: psum/fclip reads done, safe to overwrite
    // write-out: lane holds o = n0+ms*16+quad*4+r (r consecutive!), i = ni*16+l15
#pragma unroll
    for (int ms = 0; ms < 4; ms++) {
      const int ob = n0 + ms * 16 + quad * 4;
      const float4 bb = *(const float4*)&b1[ob];      // fold b1 into U'
      const int kb = ob >> 3, jo = ob & 7;            // jo in {0,4} -> 8B-aligned
#pragma unroll
      for (int ni = 0; ni < 2; ni++) {
        const int i = ni * 16 + l15;
        u32x2 uu, vv;
        uu[0] = pack2(f2bf(aU[ms][ni][0] + bb.x), f2bf(aU[ms][ni][1] + bb.y));
        uu[1] = pack2(f2bf(aU[ms][ni][2] + bb.z), f2bf(aU[ms][ni][3] + bb.w));
        vv[0] = pack2(f2bf(aV[ms][ni][0]), f2bf(aV[ms][ni][1]));
        vv[1] = pack2(f2bf(aV[ms][ni][2]), f2bf(aV[ms][ni][3]));
        *(u32x2*)&ULs[((kb << 5) + i) * 8 + jo] = uu;
        *(u32x2*)&VLs[((kb << 5) + i) * 8 + jo] = vv;
      }
    }
  }
  __syncthreads();                     // sync4: ULs/VLs ready; NO barriers after this

  // ------------- Main loop: e = relu(h @ W2^T + b2), barrier-free -------------
  // A = W2L (M = o), B = h built in-register. D: row -> o (4 consec per lane), col -> p.
  const int R0 = q * 256;
  const f32x4 zf = {0.f, 0.f, 0.f, 0.f};
#pragma unroll 1
  for (int c = 0; c < 4; c++) {        // 4 chunks of 64 pair-rows
    f32x4 acc[4][4];                   // [ms=o-tile][ns=pair-tile]
#pragma unroll
    for (int ms = 0; ms < 4; ms++)
#pragma unroll
      for (int ns = 0; ns < 4; ns++) acc[ms][ns] = zf;
    const int i0 = q * 8 + c * 2;      // two i-values this chunk: i0, i0+1
#pragma unroll 2
    for (int ks = 0; ks < 8; ks++) {
      const int kb = ks * 4 + quad;    // 0..31 (K=256)
      const bf16x8 a0 = *(const bf16x8*)&W2L[(size_t)((kb << 8) + n0      + l15) * 8];
      const bf16x8 a1 = *(const bf16x8*)&W2L[(size_t)((kb << 8) + n0 + 16 + l15) * 8];
      const bf16x8 a2 = *(const bf16x8*)&W2L[(size_t)((kb << 8) + n0 + 32 + l15) * 8];
      const bf16x8 a3 = *(const bf16x8*)&W2L[(size_t)((kb << 8) + n0 + 48 + l15) * 8];
      const bf16x8 u0 = *(const bf16x8*)&ULs[((kb << 5) + i0    ) * 8];  // quad-bcast
      const bf16x8 u1 = *(const bf16x8*)&ULs[((kb << 5) + i0 + 1) * 8];
      const bf16x8 v0 = *(const bf16x8*)&VLs[((kb << 5) + l15     ) * 8]; // 256B runs
      const bf16x8 v1 = *(const bf16x8*)&VLs[((kb << 5) + 16 + l15) * 8];
      {
        const bf16x8 hb = hfrag2(u0, v0);   // ns=0: pairs (i0, j=l15)
        acc[0][0] = MFMA16(a0, hb, acc[0][0]);
        acc[1][0] = MFMA16(a1, hb, acc[1][0]);
        acc[2][0] = MFMA16(a2, hb, acc[2][0]);
        acc[3][0] = MFMA16(a3, hb, acc[3][0]);
      }
      {
        const bf16x8 hb = hfrag2(u1, v0);   // ns=2: (i0+1, l15)
        acc[0][2] = MFMA16(a0, hb, acc[0][2]);
        acc[1][2] = MFMA16(a1, hb, acc[1][2]);
        acc[2][2] = MFMA16(a2, hb, acc[2][2]);
        acc[3][2] = MFMA16(a3, hb, acc[3][2]);
      }
      {
        const bf16x8 hb = hfrag2(u0, v1);   // ns=1: (i0, 16+l15)
        acc[0][1] = MFMA16(a0, hb, acc[0][1]);
        acc[1][1] = MFMA16(a1, hb, acc[1][1]);
        acc[2][1] = MFMA16(a2, hb, acc[2][1]);
        acc[3][1] = MFMA16(a3, hb, acc[3][1]);
      }
      {
        const bf16x8 hb = hfrag2(u1, v1);   // ns=3: (i0+1, 16+l15)
        acc[0][3] = MFMA16(a0, hb, acc[0][3]);
        acc[1][3] = MFMA16(a1, hb, acc[1][3]);
        acc[2][3] = MFMA16(a2, hb, acc[2][3]);
        acc[3][3] = MFMA16(a3, hb, acc[3][3]);
      }
    }

    // epilogue: bias + relu + f32x4 nontemporal stores (16B/lane, 64B runs/row)
    const size_t prow = (size_t)bt * 1024 + R0 + c * 64;
#pragma unroll
    for (int ms = 0; ms < 4; ms++) {
      const int o = n0 + ms * 16 + quad * 4;
      const float4 bb = *(const float4*)&b2[o];
#pragma unroll
      for (int ns = 0; ns < 4; ns++) {
        float* po = out + (prow + ns * 16 + l15) * 256 + o;
        f32x4 r;
        r[0] = fmaxf(acc[ms][ns][0] + bb.x, 0.f);
        r[1] = fmaxf(acc[ms][ns][1] + bb.y, 0.f);
        r[2] = fmaxf(acc[ms][ns][2] + bb.z, 0.f);
        r[3] = fmaxf(acc[ms][ns][3] + bb.w, 0.f);
        __builtin_nontemporal_store(r, (f32x4*)po);
      }
    }
  }
}

extern "C" void kernel_launch(void* const* d_in, const int* in_sizes, int n_in,
                              void* d_out, int out_size, void* d_ws, size_t ws_size,
                              hipStream_t stream) {
  const float* objs = (const float*)d_in[0];
  const float* W1   = (const float*)d_in[1];
  const float* b1   = (const float*)d_in[2];
  const float* W2   = (const float*)d_in[3];
  const float* b2   = (const float*)d_in[4];
  float* out = (float*)d_out;
  short* W2L = (short*)d_ws;                 // 128 KB bf16 swizzled W2
  short* W1L = W2L + 8192 * 8;               // 128 KB bf16 swizzled W1 (U|V parts)

  prep_weights<<<64, 256, 0, stream>>>(W2, W1, W2L, W1L);
  orn_main<<<960, 256, 0, stream>>>(objs, b1, b2, W1L, W2L, out);
}

// Round 5
// 316.345 us; speedup vs baseline: 1.1038x; 1.1038x over previous
//
#include <hip/hip_runtime.h>

// ObjectRelationNetwork on MI355X — barrier-free main loop, register-pressure-fixed.
//
// History: r0 = 316.8us (64KB-LDS, 2 barriers/chunk, 2 blk/CU). r3 = 349.2us:
// barrier-free rewrite REGRESSED because __launch_bounds__(256,4) capped VGPRs at
// 128 while the inner loop (acc[4][4]=64 + unroll-2 operands=64 + temps) needs
// ~150 -> scratch spills in the MFMA loop. This round: launch_bounds(256,3)
// (cap ~168, 3 blk/CU = 12 waves/CU) + ks-loop unroll 1 (live set ~125).
// All bf16 converts stay RNE bit-twiddle f2bf (r2 lesson: v_cvt_pk_bf16_f32
// truncation bias -> absmax 0.407 vs 0.016).
// (r4: container infra failure, identical kernel resubmitted.)

typedef __attribute__((ext_vector_type(8))) short bf16x8;   // 8 bf16 = 4 VGPRs
typedef __attribute__((ext_vector_type(4))) float f32x4;    // MFMA C/D, nt stores
typedef __attribute__((ext_vector_type(4))) unsigned u32x4;
typedef __attribute__((ext_vector_type(2))) unsigned u32x2;

#define MFMA16(a, b, c) __builtin_amdgcn_mfma_f32_16x16x32_bf16((a), (b), (c), 0, 0, 0)
#define E_ELEMS 62914560ull   // 240*1024*256 e floats, then 245760 all_is_obj floats

__device__ __forceinline__ short f2bf(float f) {          // RNE float->bf16
  unsigned u = __builtin_bit_cast(unsigned, f);
  u += 0x7fffu + ((u >> 16) & 1u);
  return (short)(u >> 16);
}
__device__ __forceinline__ unsigned pack2(short lo, short hi) {
  return (unsigned)(unsigned short)lo | ((unsigned)(unsigned short)hi << 16);
}

// h-fragment: relu(u+v) elementwise on 8 bf16, repacked to bf16 (RNE).
__device__ __forceinline__ bf16x8 hfrag2(bf16x8 u, bf16x8 v) {
  u32x4 uu = __builtin_bit_cast(u32x4, u);
  u32x4 vv = __builtin_bit_cast(u32x4, v);
  u32x4 r;
#pragma unroll
  for (int k = 0; k < 4; k++) {
    float lo = __builtin_bit_cast(float, uu[k] << 16) +
               __builtin_bit_cast(float, vv[k] << 16);
    float hi = __builtin_bit_cast(float, uu[k] & 0xffff0000u) +
               __builtin_bit_cast(float, vv[k] & 0xffff0000u);
    r[k] = pack2(f2bf(fmaxf(lo, 0.f)), f2bf(fmaxf(hi, 0.f)));
  }
  return __builtin_bit_cast(bf16x8, r);
}

// ---- prep: W2 (256x256) -> W2L[kb=k>>3][n][k&7]  (K=256, fragment layout)
//            W1 (256x256) -> W1L[part][kb][n][jj]  (part 0: d 0..127 (U),
//                                                   part 1: d 128..255 (V))
__global__ void prep_weights(const float* __restrict__ W2, const float* __restrict__ W1,
                             short* __restrict__ W2L, short* __restrict__ W1L) {
  int t = blockIdx.x * 256 + threadIdx.x;   // 0..16383
  const float* src;
  short* dst;
  if (t < 8192) {
    int kb = t >> 8, n = t & 255;
    src = W2 + (size_t)n * 256 + kb * 8;
    dst = W2L + (size_t)t * 8;
  } else {
    int u = t - 8192;                       // 0..8191
    int part = u >> 12, kb = (u >> 8) & 15, n = u & 255;
    src = W1 + (size_t)n * 256 + part * 128 + kb * 8;
    dst = W1L + (size_t)u * 8;
  }
  float4 x = *(const float4*)src;
  float4 y = *(const float4*)(src + 4);
  bf16x8 f;
  f[0] = f2bf(x.x); f[1] = f2bf(x.y); f[2] = f2bf(x.z); f[3] = f2bf(x.w);
  f[4] = f2bf(y.x); f[5] = f2bf(y.y); f[6] = f2bf(y.z); f[7] = f2bf(y.w);
  *(bf16x8*)dst = f;
}

// ---- main: 960 blocks (4 per (b,t)), 256 threads. LDS 32 KB; 3 blocks/CU.
__global__ __launch_bounds__(256, 3) void orn_main(
    const float* __restrict__ objs, const float* __restrict__ b1,
    const float* __restrict__ b2, const short* __restrict__ W1L,
    const short* __restrict__ W2L, float* __restrict__ out) {
  __shared__ short ULs[32 * 32 * 8];   // [kb=o>>3][i][o&7]  bf16 of U' = O@W1a^T + b1
  __shared__ short VLs[32 * 32 * 8];   // [kb][j][jj]        bf16 of V  = O@W1b^T

  float* psum  = (float*)ULs;          // phase-1 scratch aliases (dead after sync3)
  float* fclip = (float*)VLs;

  const int tid = threadIdx.x;
  const int bid = blockIdx.x;
  const int bt  = bid >> 2;            // 0..239
  const int q   = bid & 3;             // row-quarter of this (b,t) slab
  const int b   = bt / 15;
  const int tm  = bt - b * 15;         // t-1
  const float* O = objs + (size_t)(b * 16 + tm + 1) * (32 * 128);

  const int lane = tid & 63;
  const int w    = tid >> 6;           // wave 0..3
  const int l15  = lane & 15;
  const int quad = lane >> 4;
  const int n0   = w * 64;             // this wave's o-col base (N split 4x64)

  // ---------------- Phase 1: fp32 row sums -> all_is_obj ----------------
  {
    int i = tid >> 3, c = tid & 7;
    const float* p = O + i * 128 + c * 16;
    float s = 0.f;
#pragma unroll
    for (int e = 0; e < 4; e++) {
      float4 v = *(const float4*)(p + e * 4);
      s += v.x + v.y + v.z + v.w;
    }
    psum[tid] = s;
  }
  __syncthreads();                     // sync1
  if (tid < 32) {
    float s = 0.f;
#pragma unroll
    for (int c = 0; c < 8; c++) s += psum[tid * 8 + c];
    fclip[tid] = fminf(fmaxf(s, 0.f), 1.f);
  }
  __syncthreads();                     // sync2
  {
    int p = q * 256 + tid;             // this WG's 256 pairs
    int i = p >> 5, j = p & 31;
    float v = fclip[i] * fclip[j] * (float)(tm + 1);
    out[E_ELEMS + (size_t)bt * 1024 + p] = fminf(fmaxf(v, 0.f), 1.f);
  }

  // ------- Phase 2: U',V (32 objs x 256 hidden) via MFMA, swapped operands -------
  // A = W1L (M = o rows), B = O (N = i cols).  D: row=quad*4+r -> o, col=l15 -> i.
  {
    // B-fragments from O: B[k = ks*32+quad*8+jj][i = ni*16+l15]
    bf16x8 bfr[2][4];
#pragma unroll
    for (int ni = 0; ni < 2; ni++)
#pragma unroll
      for (int ks = 0; ks < 4; ks++) {
        const float* p = O + (ni * 16 + l15) * 128 + ks * 32 + quad * 8;
        float4 x = *(const float4*)p;
        float4 y = *(const float4*)(p + 4);
        bf16x8 f;
        f[0] = f2bf(x.x); f[1] = f2bf(x.y); f[2] = f2bf(x.z); f[3] = f2bf(x.w);
        f[4] = f2bf(y.x); f[5] = f2bf(y.y); f[6] = f2bf(y.z); f[7] = f2bf(y.w);
        bfr[ni][ks] = f;
      }
    const f32x4 zf = {0.f, 0.f, 0.f, 0.f};
    f32x4 aU[4][2], aV[4][2];
#pragma unroll
    for (int ms = 0; ms < 4; ms++)
#pragma unroll
      for (int ni = 0; ni < 2; ni++) { aU[ms][ni] = zf; aV[ms][ni] = zf; }
#pragma unroll
    for (int ks = 0; ks < 4; ks++) {
      const int kb = ks * 4 + quad;    // 0..15 (K=128 per part)
#pragma unroll
      for (int ms = 0; ms < 4; ms++) {
        const int n = n0 + ms * 16 + l15;
        bf16x8 au = *(const bf16x8*)&W1L[(size_t)((kb << 8) + n) * 8];
        bf16x8 av = *(const bf16x8*)&W1L[(size_t)(4096 + (kb << 8) + n) * 8];
#pragma unroll
        for (int ni = 0; ni < 2; ni++) {
          aU[ms][ni] = MFMA16(au, bfr[ni][ks], aU[ms][ni]);
          aV[ms][ni] = MFMA16(av, bfr[ni][ks], aV[ms][ni]);
        }
      }
    }
    __syncthreads();                   // sync3: psum/fclip reads done, safe to overwrite
    // write-out: lane holds o = n0+ms*16+quad*4+r (r consecutive!), i = ni*16+l15
#pragma unroll
    for (int ms = 0; ms < 4; ms++) {
      const int ob = n0 + ms * 16 + quad * 4;
      const float4 bb = *(const float4*)&b1[ob];      // fold b1 into U'
      const int kb = ob >> 3, jo = ob & 7;            // jo in {0,4} -> 8B-aligned
#pragma unroll
      for (int ni = 0; ni < 2; ni++) {
        const int i = ni * 16 + l15;
        u32x2 uu, vv;
        uu[0] = pack2(f2bf(aU[ms][ni][0] + bb.x), f2bf(aU[ms][ni][1] + bb.y));
        uu[1] = pack2(f2bf(aU[ms][ni][2] + bb.z), f2bf(aU[ms][ni][3] + bb.w));
        vv[0] = pack2(f2bf(aV[ms][ni][0]), f2bf(aV[ms][ni][1]));
        vv[1] = pack2(f2bf(aV[ms][ni][2]), f2bf(aV[ms][ni][3]));
        *(u32x2*)&ULs[((kb << 5) + i) * 8 + jo] = uu;
        *(u32x2*)&VLs[((kb << 5) + i) * 8 + jo] = vv;
      }
    }
  }
  __syncthreads();                     // sync4: ULs/VLs ready; NO barriers after this

  // ------------- Main loop: e = relu(h @ W2^T + b2), barrier-free -------------
  // A = W2L (M = o), B = h built in-register. D: row -> o (4 consec per lane), col -> p.
  const int R0 = q * 256;
  const f32x4 zf = {0.f, 0.f, 0.f, 0.f};
#pragma unroll 1
  for (int c = 0; c < 4; c++) {        // 4 chunks of 64 pair-rows
    f32x4 acc[4][4];                   // [ms=o-tile][ns=pair-tile]
#pragma unroll
    for (int ms = 0; ms < 4; ms++)
#pragma unroll
      for (int ns = 0; ns < 4; ns++) acc[ms][ns] = zf;
    const int i0 = q * 8 + c * 2;      // two i-values this chunk: i0, i0+1
#pragma unroll 1
    for (int ks = 0; ks < 8; ks++) {   // unroll 1: keep live set under the 168 cap
      const int kb = ks * 4 + quad;    // 0..31 (K=256)
      const bf16x8 a0 = *(const bf16x8*)&W2L[(size_t)((kb << 8) + n0      + l15) * 8];
      const bf16x8 a1 = *(const bf16x8*)&W2L[(size_t)((kb << 8) + n0 + 16 + l15) * 8];
      const bf16x8 a2 = *(const bf16x8*)&W2L[(size_t)((kb << 8) + n0 + 32 + l15) * 8];
      const bf16x8 a3 = *(const bf16x8*)&W2L[(size_t)((kb << 8) + n0 + 48 + l15) * 8];
      const bf16x8 u0 = *(const bf16x8*)&ULs[((kb << 5) + i0    ) * 8];  // quad-bcast
      const bf16x8 u1 = *(const bf16x8*)&ULs[((kb << 5) + i0 + 1) * 8];
      const bf16x8 v0 = *(const bf16x8*)&VLs[((kb << 5) + l15     ) * 8]; // 256B runs
      const bf16x8 v1 = *(const bf16x8*)&VLs[((kb << 5) + 16 + l15) * 8];
      {
        const bf16x8 hb = hfrag2(u0, v0);   // ns=0: pairs (i0, j=l15)
        acc[0][0] = MFMA16(a0, hb, acc[0][0]);
        acc[1][0] = MFMA16(a1, hb, acc[1][0]);
        acc[2][0] = MFMA16(a2, hb, acc[2][0]);
        acc[3][0] = MFMA16(a3, hb, acc[3][0]);
      }
      {
        const bf16x8 hb = hfrag2(u1, v0);   // ns=2: (i0+1, l15)
        acc[0][2] = MFMA16(a0, hb, acc[0][2]);
        acc[1][2] = MFMA16(a1, hb, acc[1][2]);
        acc[2][2] = MFMA16(a2, hb, acc[2][2]);
        acc[3][2] = MFMA16(a3, hb, acc[3][2]);
      }
      {
        const bf16x8 hb = hfrag2(u0, v1);   // ns=1: (i0, 16+l15)
        acc[0][1] = MFMA16(a0, hb, acc[0][1]);
        acc[1][1] = MFMA16(a1, hb, acc[1][1]);
        acc[2][1] = MFMA16(a2, hb, acc[2][1]);
        acc[3][1] = MFMA16(a3, hb, acc[3][1]);
      }
      {
        const bf16x8 hb = hfrag2(u1, v1);   // ns=3: (i0+1, 16+l15)
        acc[0][3] = MFMA16(a0, hb, acc[0][3]);
        acc[1][3] = MFMA16(a1, hb, acc[1][3]);
        acc[2][3] = MFMA16(a2, hb, acc[2][3]);
        acc[3][3] = MFMA16(a3, hb, acc[3][3]);
      }
    }

    // epilogue: bias + relu + f32x4 nontemporal stores (16B/lane, 64B runs/row)
    const size_t prow = (size_t)bt * 1024 + R0 + c * 64;
#pragma unroll
    for (int ms = 0; ms < 4; ms++) {
      const int o = n0 + ms * 16 + quad * 4;
      const float4 bb = *(const float4*)&b2[o];
#pragma unroll
      for (int ns = 0; ns < 4; ns++) {
        float* po = out + (prow + ns * 16 + l15) * 256 + o;
        f32x4 r;
        r[0] = fmaxf(acc[ms][ns][0] + bb.x, 0.f);
        r[1] = fmaxf(acc[ms][ns][1] + bb.y, 0.f);
        r[2] = fmaxf(acc[ms][ns][2] + bb.z, 0.f);
        r[3] = fmaxf(acc[ms][ns][3] + bb.w, 0.f);
        __builtin_nontemporal_store(r, (f32x4*)po);
      }
    }
  }
}

extern "C" void kernel_launch(void* const* d_in, const int* in_sizes, int n_in,
                              void* d_out, int out_size, void* d_ws, size_t ws_size,
                              hipStream_t stream) {
  const float* objs = (const float*)d_in[0];
  const float* W1   = (const float*)d_in[1];
  const float* b1   = (const float*)d_in[2];
  const float* W2   = (const float*)d_in[3];
  const float* b2   = (const float*)d_in[4];
  float* out = (float*)d_out;
  short* W2L = (short*)d_ws;                 // 128 KB bf16 swizzled W2
  short* W1L = W2L + 8192 * 8;               // 128 KB bf16 swizzled W1 (U|V parts)

  prep_weights<<<64, 256, 0, stream>>>(W2, W1, W2L, W1L);
  orn_main<<<960, 256, 0, stream>>>(objs, b1, b2, W1L, W2L, out);
}